// Round 8
// baseline (184.466 us; speedup 1.0000x reference)
//
#include <hip/hip_runtime.h>
#include <hip/hip_bf16.h>

#define BB 32
#define NN 1024
#define QQ 64
#define HH 768

typedef __attribute__((ext_vector_type(8))) short short8;
typedef __attribute__((ext_vector_type(4))) float f32x4;

#define GLOAD_LDS16(gp, lp) \
  __builtin_amdgcn_global_load_lds((const __attribute__((address_space(1))) unsigned int*)(gp), \
                                   (__attribute__((address_space(3))) unsigned int*)(lp), 16, 0, 0)

__device__ __forceinline__ unsigned short f2b(float f) {
  unsigned int u = __float_as_uint(f);
  unsigned int r = u + 0x7fffu + ((u >> 16) & 1u);
  return (unsigned short)(r >> 16);
}

__device__ __forceinline__ short8 cvt8(float4 f0, float4 f1) {
  short8 v;
  v[0] = (short)f2b(f0.x); v[1] = (short)f2b(f0.y);
  v[2] = (short)f2b(f0.z); v[3] = (short)f2b(f0.w);
  v[4] = (short)f2b(f1.x); v[5] = (short)f2b(f1.y);
  v[6] = (short)f2b(f1.z); v[7] = (short)f2b(f1.w);
  return v;
}

// K0: [0,768): qwB = bf16(qc*w_nq + w_n), LINEAR [b][q][h]
//     [768,1536): qcT_sw = bf16(qc^T), pre-XOR-swizzled [b][hc][128 h][8 units]
//     [1536,2048): sq[b][q] = dot(qc[b][q][:], w_q)
__global__ void k_prep(const float* __restrict__ qc, const float* __restrict__ w,
                       unsigned short* __restrict__ qwB, unsigned short* __restrict__ qcT,
                       float* __restrict__ sq) {
  const int bid = blockIdx.x, tid = threadIdx.x;
  if (bid < 768) {
    int gid = bid * 256 + tid;            // 8-elem unit id, 0..196607
    int h = (gid * 8) % HH;
    const float* src = qc + (size_t)gid * 8;
    float4 g0 = *(const float4*)src, g1 = *(const float4*)(src + 4);
    float4 n0 = *(const float4*)(w + h), n1 = *(const float4*)(w + h + 4);
    float4 m0 = *(const float4*)(w + 2 * HH + h), m1 = *(const float4*)(w + 2 * HH + h + 4);
    short8 v;
    v[0] = (short)f2b(g0.x * m0.x + n0.x); v[1] = (short)f2b(g0.y * m0.y + n0.y);
    v[2] = (short)f2b(g0.z * m0.z + n0.z); v[3] = (short)f2b(g0.w * m0.w + n0.w);
    v[4] = (short)f2b(g1.x * m1.x + n1.x); v[5] = (short)f2b(g1.y * m1.y + n1.y);
    v[6] = (short)f2b(g1.z * m1.z + n1.z); v[7] = (short)f2b(g1.w * m1.w + n1.w);
    *(short8*)(qwB + (size_t)gid * 8) = v;
  } else if (bid < 1536) {
    int gid = (bid - 768) * 256 + tid;    // dest unit id (linear store, gathered load)
    int b = gid / 6144, p = gid % 6144;
    int hc = p >> 10, pr = p & 1023, r = pr >> 3, x = pr & 7;
    int xu = x ^ (r & 7);
    int h = hc * 128 + r;
    const float* col = qc + ((size_t)(b * 64 + xu * 8) * HH + h);
    short8 v;
#pragma unroll
    for (int j = 0; j < 8; ++j) v[j] = (short)f2b(col[(size_t)j * HH]);
    *(short8*)((char*)qcT + (size_t)gid * 16) = v;
  } else {
    int wid = ((bid - 1536) * 256 + tid) >> 6; // 0..2047 (b*64+q)
    int l = tid & 63;
    const float* row = qc + (size_t)wid * HH;
    float s = 0.f;
#pragma unroll
    for (int i = 0; i < 12; ++i) s += row[i * 64 + l] * w[HH + i * 64 + l];
#pragma unroll
    for (int m = 1; m < 64; m <<= 1) s += __shfl_xor(s, m);
    if (l == 0) sq[wid] = s;
  }
}

// K1: GEMM1 barrier-free: A global->reg, B' fragments direct from global (L2-hot).
// Then per-wave softmax -> probs(bf16)->ws, per-tile q2n partials + (m_t, sumexp).
__global__ __launch_bounds__(256) void k_sim(
    const float* __restrict__ nc, const unsigned short* __restrict__ qwB,
    const float* __restrict__ sq, float* __restrict__ partial,
    float* __restrict__ mtse, unsigned short* __restrict__ probs)
{
  __shared__ float rowmF[64];
  __shared__ float wvF[64];

  const int tid = threadIdx.x;
  const int wv_ = tid >> 6, l = tid & 63;
  const int l15 = l & 15, lg = l >> 4;
  const int b = blockIdx.x >> 4, tile = blockIdx.x & 15;
  const int row0 = tile * 64;

  const float* ncB = nc + (size_t)(b * NN + row0) * HH;
  const int arow = wv_ * 16 + l15;
  const float* aRow = ncB + (size_t)arow * HH + lg * 8;
  const unsigned short* bRow = qwB + (size_t)b * QQ * HH + (size_t)l15 * HH + lg * 8;

  // ---------------- GEMM1: barrier-free, compiler-pipelined ----------------
  f32x4 acc[4] = {};
#pragma unroll
  for (int kc = 0; kc < 6; ++kc) {
#pragma unroll
    for (int ks = 0; ks < 4; ++ks) {
      int col = kc * 128 + ks * 32;
      float4 f0 = *(const float4*)(aRow + col);
      float4 f1 = *(const float4*)(aRow + col + 4);
      short8 a = cvt8(f0, f1);
#pragma unroll
      for (int nt = 0; nt < 4; ++nt) {
        short8 bf = *(const short8*)(bRow + nt * 16 * HH + col);
        acc[nt] = __builtin_amdgcn_mfma_f32_16x16x32_bf16(a, bf, acc[nt], 0, 0, 0);
      }
    }
  }

  // ---- softmax over q (per-wave); D layout: row n = wv_*16+lg*4+j, col q = nt*16+l15 ----
  unsigned short* pT = probs + (size_t)(b * 16 + tile) * (QQ * QQ);
  float sqv[4];
#pragma unroll
  for (int nt = 0; nt < 4; ++nt) sqv[nt] = sq[b * QQ + nt * 16 + l15];
#pragma unroll
  for (int j = 0; j < 4; ++j) {
    float mm = -1e30f;
#pragma unroll
    for (int nt = 0; nt < 4; ++nt) { acc[nt][j] += sqv[nt]; mm = fmaxf(mm, acc[nt][j]); }
    mm = fmaxf(mm, __shfl_xor(mm, 1));
    mm = fmaxf(mm, __shfl_xor(mm, 2));
    mm = fmaxf(mm, __shfl_xor(mm, 4));
    mm = fmaxf(mm, __shfl_xor(mm, 8));
    float ss = 0.f;
#pragma unroll
    for (int nt = 0; nt < 4; ++nt) { float p = __expf(acc[nt][j] - mm); acc[nt][j] = p; ss += p; }
    ss += __shfl_xor(ss, 1); ss += __shfl_xor(ss, 2);
    ss += __shfl_xor(ss, 4); ss += __shfl_xor(ss, 8);
    float inv = 1.0f / ss;
    int r = wv_ * 16 + lg * 4 + j;
#pragma unroll
    for (int nt = 0; nt < 4; ++nt)
      pT[r * 64 + nt * 16 + l15] = f2b(acc[nt][j] * inv);
    if (l15 == 0) rowmF[r] = mm;
  }
  __syncthreads();

  // ---- per-tile q2n partials (tile rows L2-hot) ----
  float m_t = -1e30f;
#pragma unroll
  for (int i = 0; i < 16; ++i) {
    f32x4 v = ((f32x4*)rowmF)[i];
    m_t = fmaxf(m_t, fmaxf(fmaxf(v[0], v[1]), fmaxf(v[2], v[3])));
  }
  if (tid < 64) wvF[tid] = __expf(rowmF[tid] - m_t);
  __syncthreads();
  {
    float sv = wvF[l];
#pragma unroll
    for (int m = 1; m < 64; m <<= 1) sv += __shfl_xor(sv, m);
    if (tid == 0) {
      mtse[(b * 16 + tile) * 2] = m_t;
      mtse[(b * 16 + tile) * 2 + 1] = sv;
    }
  }
  {
    float p0 = 0.f, p1 = 0.f, p2 = 0.f;
    for (int n = 0; n < 64; ++n) {
      float wvv = wvF[n];
      const float* pr = ncB + n * HH + tid;
      p0 += wvv * pr[0]; p1 += wvv * pr[256]; p2 += wvv * pr[512];
    }
    float* pp = partial + (size_t)(b * 16 + tile) * HH + tid;
    pp[0] = p0; pp[256] = p1; pp[512] = p2;
  }
}

// K2: GEMM2 (swapped: D[h][n]) + q2n combine (folded) + all four output chunks.
// Grid: (b, tile, hc) = 3072 blocks.
__global__ __launch_bounds__(256) void k_out(
    const float* __restrict__ nc, const unsigned short* __restrict__ qcT,
    const unsigned short* __restrict__ probs, const float* __restrict__ partial,
    const float* __restrict__ mtse, float* __restrict__ out)
{
  __shared__ __align__(16) char smem[16384];   // qcT chunk [128 h][8 units], pre-swizzled
  __shared__ float q2nL[128];

  const int tid = threadIdx.x;
  const int wv_ = tid >> 6, l = tid & 63;
  const int l15 = l & 15, lg = l >> 4;
  const int bid = blockIdx.x;
  const int hc = bid % 6;
  const int bt = bid / 6;              // b*16 + tile
  const int b = bt >> 4, tile = bt & 15;
  const int row0 = tile * 64;

  // stage qcT chunk via async direct-to-LDS (source pre-swizzled)
  {
    const char* src = (const char*)qcT + ((size_t)(b * 6 + hc) << 14) + wv_ * 4096 + l * 16;
#pragma unroll
    for (int i = 0; i < 4; ++i)
      GLOAD_LDS16(src + i * 1024, &smem[wv_ * 4096 + i * 1024]);
  }

  // q2n slice for this h-chunk (replaces k_comb)
  if (tid < 128) {
    float M = -1e30f, mt[16], se[16];
#pragma unroll
    for (int i = 0; i < 16; ++i) {
      mt[i] = mtse[(b * 16 + i) * 2];
      se[i] = mtse[(b * 16 + i) * 2 + 1];
      M = fmaxf(M, mt[i]);
    }
    float denom = 0.f;
#pragma unroll
    for (int i = 0; i < 16; ++i) { mt[i] = __expf(mt[i] - M); denom += mt[i] * se[i]; }
    float inv = 1.0f / denom;
    float a = 0.f;
#pragma unroll
    for (int i = 0; i < 16; ++i)
      a += mt[i] * partial[(size_t)(b * 16 + i) * HH + hc * 128 + tid];
    q2nL[tid] = a * inv;
  }

  // probs A-frags (pre-normalized bf16), direct from global (L2-hot)
  const unsigned short* pT = probs + (size_t)bt * (QQ * QQ);
  short8 a2_0 = *(const short8*)((const char*)pT + (wv_ * 16 + l15) * 128 + lg * 16);
  short8 a2_1 = *(const short8*)((const char*)pT + (wv_ * 16 + l15) * 128 + 64 + lg * 16);

  asm volatile("s_waitcnt vmcnt(0)" ::: "memory");
  __syncthreads();

  const int n = wv_ * 16 + l15;
  const float* ncrow = nc + (size_t)(b * NN + row0 + n) * HH;
  float* orow = out + (size_t)(b * NN + row0 + n) * 3072;

#pragma unroll
  for (int hg = 0; hg < 8; ++hg) {
    f32x4 c2 = {};
#pragma unroll
    for (int ks2 = 0; ks2 < 2; ++ks2) {
      int hrow = hg * 16 + l15;
      int kbyte = ks2 * 64 + lg * 16;
      short8 hf = *(short8*)(&smem[0] + hrow * 128 + (kbyte ^ ((l & 7) << 4)));
      c2 = __builtin_amdgcn_mfma_f32_16x16x32_bf16(hf, ks2 ? a2_1 : a2_0, c2, 0, 0, 0);
    }
    // thread owns n = wv_*16+l15, h = hc*128 + hg*16 + lg*4 + (0..3)
    int hl = hg * 16 + lg * 4;
    int hbase = hc * 128 + hl;
    f32x4 ncv = *(const f32x4*)(ncrow + hbase);
    f32x4 qv  = *(const f32x4*)(&q2nL[hl]);
    *(f32x4*)(orow + hbase)          = ncv;
    *(f32x4*)(orow + HH + hbase)     = c2;
    *(f32x4*)(orow + 2 * HH + hbase) = ncv * c2;
    *(f32x4*)(orow + 2304 + hbase)   = ncv * qv;
  }
}

extern "C" void kernel_launch(void* const* d_in, const int* in_sizes, int n_in,
                              void* d_out, int out_size, void* d_ws, size_t ws_size,
                              hipStream_t stream) {
  (void)in_sizes; (void)n_in; (void)out_size; (void)ws_size;
  const float* nc = (const float*)d_in[0];
  const float* qc = (const float*)d_in[1];
  const float* w  = (const float*)d_in[3];
  float* out = (float*)d_out;
  char* ws = (char*)d_ws;
  unsigned short* qwB = (unsigned short*)(ws);                 // 3,145,728 B (linear)
  unsigned short* qcT = (unsigned short*)(ws + 3145728);       // 3,145,728 B (pre-swizzled)
  float* sqv     = (float*)(ws + 6291456);                     // 8 KB
  float* partial = (float*)(ws + 6299648);                     // 1,572,864 B
  float* mtse    = (float*)(ws + 7872512);                     // 4 KB
  unsigned short* probs = (unsigned short*)(ws + 7876608);     // 4,194,304 B

  k_prep<<<2048, 256, 0, stream>>>(qc, w, qwB, qcT, sqv);
  k_sim<<<512, 256, 0, stream>>>(nc, qwB, sqv, partial, mtse, probs);
  k_out<<<3072, 256, 0, stream>>>(nc, qcT, probs, partial, mtse, out);
}

// Round 9
// 157.410 us; speedup vs baseline: 1.1719x; 1.1719x over previous
//
#include <hip/hip_runtime.h>
#include <hip/hip_bf16.h>

#define BB 32
#define NN 1024
#define QQ 64
#define HH 768

typedef __attribute__((ext_vector_type(8))) short short8;
typedef __attribute__((ext_vector_type(4))) float f32x4;

#define GLOAD_LDS16(gp, lp) \
  __builtin_amdgcn_global_load_lds((const __attribute__((address_space(1))) unsigned int*)(gp), \
                                   (__attribute__((address_space(3))) unsigned int*)(lp), 16, 0, 0)

__device__ __forceinline__ unsigned short f2b(float f) {
  unsigned int u = __float_as_uint(f);
  unsigned int r = u + 0x7fffu + ((u >> 16) & 1u);
  return (unsigned short)(r >> 16);
}

// K0: [0,768): qwB_sw = bf16(qc*w_nq + w_n), pre-XOR-swizzled [b][kc][q][16 units]
//     [768,1536): qcT_sw = bf16(qc^T), pre-XOR-swizzled [b][hc][128 h][8 units]
//     [1536,2048): sq[b][q] = dot(qc[b][q][:], w_q)
__global__ void k_prep(const float* __restrict__ qc, const float* __restrict__ w,
                       unsigned short* __restrict__ qwB, unsigned short* __restrict__ qcT,
                       float* __restrict__ sq) {
  const int bid = blockIdx.x, tid = threadIdx.x;
  if (bid < 768) {
    int gid = bid * 256 + tid;            // 16B-unit id, 0..196607
    int b = gid / 6144, rem = gid % 6144;
    int q = rem / 96, kk = rem % 96;      // kk: 8-elem unit within H
    int kc = kk >> 4, uu = kk & 15;
    const float* src = qc + ((size_t)(b * 64 + q) * HH + kk * 8);
    float4 g0 = *(const float4*)src, g1 = *(const float4*)(src + 4);
    int h = kk * 8;
    float4 n0 = *(const float4*)(w + h), n1 = *(const float4*)(w + h + 4);
    float4 m0 = *(const float4*)(w + 2 * HH + h), m1 = *(const float4*)(w + 2 * HH + h + 4);
    short8 v;
    v[0] = (short)f2b(g0.x * m0.x + n0.x); v[1] = (short)f2b(g0.y * m0.y + n0.y);
    v[2] = (short)f2b(g0.z * m0.z + n0.z); v[3] = (short)f2b(g0.w * m0.w + n0.w);
    v[4] = (short)f2b(g1.x * m1.x + n1.x); v[5] = (short)f2b(g1.y * m1.y + n1.y);
    v[6] = (short)f2b(g1.z * m1.z + n1.z); v[7] = (short)f2b(g1.w * m1.w + n1.w);
    size_t du = (size_t)(b * 6 + kc) * 1024 + q * 16 + (uu ^ (q & 7));
    *(short8*)((char*)qwB + du * 16) = v;
  } else if (bid < 1536) {
    int gid = (bid - 768) * 256 + tid;    // dest unit id (linear store, gathered load)
    int b = gid / 6144, p = gid % 6144;
    int hc = p >> 10, pr = p & 1023, r = pr >> 3, x = pr & 7;
    int xu = x ^ (r & 7);
    int h = hc * 128 + r;
    const float* col = qc + ((size_t)(b * 64 + xu * 8) * HH + h);
    short8 v;
#pragma unroll
    for (int j = 0; j < 8; ++j) v[j] = (short)f2b(col[(size_t)j * HH]);
    *(short8*)((char*)qcT + (size_t)gid * 16) = v;
  } else {
    int wid = ((bid - 1536) * 256 + tid) >> 6; // 0..2047 (b*64+q)
    int l = tid & 63;
    const float* row = qc + (size_t)wid * HH;
    float s = 0.f;
#pragma unroll
    for (int i = 0; i < 12; ++i) s += row[i * 64 + l] * w[HH + i * 64 + l];
#pragma unroll
    for (int m = 1; m < 64; m <<= 1) s += __shfl_xor(s, m);
    if (l == 0) sq[wid] = s;
  }
}

// K1: GEMM1 (sim) pipelined (R5 structure) + XCD swizzle + wave-parallel partials.
__global__ __launch_bounds__(256) void k_sim(
    const float* __restrict__ nc, const unsigned short* __restrict__ qwB,
    const float* __restrict__ sq, float* __restrict__ partial,
    float* __restrict__ mtse, unsigned short* __restrict__ probs)
{
  __shared__ __align__(16) char bbuf[2][16384];
  __shared__ float rowmF[64];
  __shared__ float wvF[64];
  __shared__ float pW[4][768];

  const int tid = threadIdx.x;
  const int wv_ = tid >> 6, l = tid & 63;
  const int l15 = l & 15, lg = l >> 4;
  // XCD-aware swizzle: all 16 tiles of a batch co-run on one XCD (512 = 8*64)
  const int lb = (blockIdx.x & 7) * 64 + (blockIdx.x >> 3);
  const int b = lb >> 4, tile = lb & 15;
  const int row0 = tile * 64;

  const float* ncB = nc + (size_t)(b * NN + row0) * HH;
  const char* qwb = (const char*)qwB + (size_t)b * 98304;   // 6*16384
  const float* aBase = ncB + (wv_ * 16 + l15) * HH + lg * 8;

  // ---- prologue: B'(0) -> buf0, A(0) -> fr[0] ----
  {
    const char* gsrc = qwb + wv_ * 4096 + l * 16;
#pragma unroll
    for (int i = 0; i < 4; ++i)
      GLOAD_LDS16(gsrc + i * 1024, &bbuf[0][wv_ * 4096 + i * 1024]);
  }
  float4 fr[2][8];
#pragma unroll
  for (int ks = 0; ks < 4; ++ks) {
    fr[0][ks * 2]     = *(const float4*)(aBase + ks * 32);
    fr[0][ks * 2 + 1] = *(const float4*)(aBase + ks * 32 + 4);
  }

  f32x4 acc[4] = {};
#pragma unroll
  for (int kc = 0; kc < 6; ++kc) {
    short8 af[4];
#pragma unroll
    for (int ks = 0; ks < 4; ++ks) {
      float4 f0 = fr[kc & 1][ks * 2], f1 = fr[kc & 1][ks * 2 + 1];
      short8 v;
      v[0] = (short)f2b(f0.x); v[1] = (short)f2b(f0.y);
      v[2] = (short)f2b(f0.z); v[3] = (short)f2b(f0.w);
      v[4] = (short)f2b(f1.x); v[5] = (short)f2b(f1.y);
      v[6] = (short)f2b(f1.z); v[7] = (short)f2b(f1.w);
      af[ks] = v;
    }
    if (kc < 5) {
#pragma unroll
      for (int ks = 0; ks < 4; ++ks) {
        fr[(kc + 1) & 1][ks * 2]     = *(const float4*)(aBase + (kc + 1) * 128 + ks * 32);
        fr[(kc + 1) & 1][ks * 2 + 1] = *(const float4*)(aBase + (kc + 1) * 128 + ks * 32 + 4);
      }
      const char* gsrc = qwb + (kc + 1) * 16384 + wv_ * 4096 + l * 16;
#pragma unroll
      for (int i = 0; i < 4; ++i)
        GLOAD_LDS16(gsrc + i * 1024, &bbuf[(kc + 1) & 1][wv_ * 4096 + i * 1024]);
      asm volatile("s_waitcnt vmcnt(12)" ::: "memory");
    } else {
      asm volatile("s_waitcnt vmcnt(0)" ::: "memory");
    }
    __builtin_amdgcn_s_barrier();
    __builtin_amdgcn_sched_barrier(0);
#pragma unroll
    for (int ks = 0; ks < 4; ++ks) {
      int kbyte = ks * 64 + lg * 16;
#pragma unroll
      for (int nt = 0; nt < 4; ++nt) {
        int brow = nt * 16 + l15;
        short8 bf = *(short8*)(&bbuf[kc & 1][0] + brow * 256 + (kbyte ^ ((l & 7) << 4)));
        acc[nt] = __builtin_amdgcn_mfma_f32_16x16x32_bf16(af[ks], bf, acc[nt], 0, 0, 0);
      }
    }
    __builtin_amdgcn_sched_barrier(0);
    __builtin_amdgcn_s_barrier();
  }

  // ---- softmax over q; D layout: row n = wv_*16+lg*4+j, col q = nt*16+l15 ----
  unsigned short* pT = probs + (size_t)(b * 16 + tile) * (QQ * QQ);
  float sqv[4];
#pragma unroll
  for (int nt = 0; nt < 4; ++nt) sqv[nt] = sq[b * QQ + nt * 16 + l15];
#pragma unroll
  for (int j = 0; j < 4; ++j) {
    float mm = -1e30f;
#pragma unroll
    for (int nt = 0; nt < 4; ++nt) { acc[nt][j] += sqv[nt]; mm = fmaxf(mm, acc[nt][j]); }
    mm = fmaxf(mm, __shfl_xor(mm, 1));
    mm = fmaxf(mm, __shfl_xor(mm, 2));
    mm = fmaxf(mm, __shfl_xor(mm, 4));
    mm = fmaxf(mm, __shfl_xor(mm, 8));
    float ss = 0.f;
#pragma unroll
    for (int nt = 0; nt < 4; ++nt) { float p = __expf(acc[nt][j] - mm); acc[nt][j] = p; ss += p; }
    ss += __shfl_xor(ss, 1); ss += __shfl_xor(ss, 2);
    ss += __shfl_xor(ss, 4); ss += __shfl_xor(ss, 8);
    float inv = 1.0f / ss;
    int r = wv_ * 16 + lg * 4 + j;
#pragma unroll
    for (int nt = 0; nt < 4; ++nt)
      pT[r * 64 + nt * 16 + l15] = f2b(acc[nt][j] * inv);
    if (l15 == 0) rowmF[r] = mm;
  }
  __syncthreads();

  // ---- per-tile q2n partials: wave-parallel (16 rows/wave, 12 h/lane) ----
  float m_t = -1e30f;
#pragma unroll
  for (int i = 0; i < 16; ++i) {
    f32x4 v = ((f32x4*)rowmF)[i];
    m_t = fmaxf(m_t, fmaxf(fmaxf(v[0], v[1]), fmaxf(v[2], v[3])));
  }
  if (tid < 64) wvF[tid] = __expf(rowmF[tid] - m_t);
  __syncthreads();
  {
    float sv = wvF[l];
#pragma unroll
    for (int m = 1; m < 64; m <<= 1) sv += __shfl_xor(sv, m);
    if (tid == 0) {
      mtse[(b * 16 + tile) * 2] = m_t;
      mtse[(b * 16 + tile) * 2 + 1] = sv;
    }
  }
  {
    float a[12];
#pragma unroll
    for (int j = 0; j < 12; ++j) a[j] = 0.f;
    for (int n0 = 0; n0 < 16; ++n0) {
      int n = wv_ * 16 + n0;
      float wvv = wvF[n];
      const float* pr = ncB + (size_t)n * HH;
#pragma unroll
      for (int j = 0; j < 12; ++j) a[j] += wvv * pr[l + j * 64];
    }
#pragma unroll
    for (int j = 0; j < 12; ++j) pW[wv_][l + j * 64] = a[j];
  }
  __syncthreads();
  {
    float* pp = partial + (size_t)(b * 16 + tile) * HH + tid;
    pp[0]   = pW[0][tid]       + pW[1][tid]       + pW[2][tid]       + pW[3][tid];
    pp[256] = pW[0][tid + 256] + pW[1][tid + 256] + pW[2][tid + 256] + pW[3][tid + 256];
    pp[512] = pW[0][tid + 512] + pW[1][tid + 512] + pW[2][tid + 512] + pW[3][tid + 512];
  }
}

// K2: GEMM2 (swapped: D[h][n]) + q2n combine (folded) + all four output chunks.
// Grid 3072 = 8*384, XCD swizzle consistent with k_sim (batch b -> XCD b/4).
__global__ __launch_bounds__(256) void k_out(
    const float* __restrict__ nc, const unsigned short* __restrict__ qcT,
    const unsigned short* __restrict__ probs, const float* __restrict__ partial,
    const float* __restrict__ mtse, float* __restrict__ out)
{
  __shared__ __align__(16) char smem[16384];   // qcT chunk [128 h][8 units], pre-swizzled
  __shared__ float q2nL[128];

  const int tid = threadIdx.x;
  const int wv_ = tid >> 6, l = tid & 63;
  const int l15 = l & 15, lg = l >> 4;
  const int lb = (blockIdx.x & 7) * 384 + (blockIdx.x >> 3);
  const int hc = lb % 6;
  const int bt = lb / 6;               // b*16 + tile
  const int b = bt >> 4, tile = bt & 15;
  const int row0 = tile * 64;

  // stage qcT chunk via async direct-to-LDS (source pre-swizzled)
  {
    const char* src = (const char*)qcT + ((size_t)(b * 6 + hc) << 14) + wv_ * 4096 + l * 16;
#pragma unroll
    for (int i = 0; i < 4; ++i)
      GLOAD_LDS16(src + i * 1024, &smem[wv_ * 4096 + i * 1024]);
  }

  // q2n slice for this h-chunk (replaces k_comb)
  if (tid < 128) {
    float M = -1e30f, mt[16], se[16];
#pragma unroll
    for (int i = 0; i < 16; ++i) {
      mt[i] = mtse[(b * 16 + i) * 2];
      se[i] = mtse[(b * 16 + i) * 2 + 1];
      M = fmaxf(M, mt[i]);
    }
    float denom = 0.f;
#pragma unroll
    for (int i = 0; i < 16; ++i) { mt[i] = __expf(mt[i] - M); denom += mt[i] * se[i]; }
    float inv = 1.0f / denom;
    float a = 0.f;
#pragma unroll
    for (int i = 0; i < 16; ++i)
      a += mt[i] * partial[(size_t)(b * 16 + i) * HH + hc * 128 + tid];
    q2nL[tid] = a * inv;
  }

  // probs A-frags (pre-normalized bf16), direct from global (L2-hot)
  const unsigned short* pT = probs + (size_t)bt * (QQ * QQ);
  short8 a2_0 = *(const short8*)((const char*)pT + (wv_ * 16 + l15) * 128 + lg * 16);
  short8 a2_1 = *(const short8*)((const char*)pT + (wv_ * 16 + l15) * 128 + 64 + lg * 16);

  asm volatile("s_waitcnt vmcnt(0)" ::: "memory");
  __syncthreads();

  const int n = wv_ * 16 + l15;
  const float* ncrow = nc + (size_t)(b * NN + row0 + n) * HH;
  float* orow = out + (size_t)(b * NN + row0 + n) * 3072;

#pragma unroll
  for (int hg = 0; hg < 8; ++hg) {
    f32x4 c2 = {};
#pragma unroll
    for (int ks2 = 0; ks2 < 2; ++ks2) {
      int hrow = hg * 16 + l15;
      int kbyte = ks2 * 64 + lg * 16;
      short8 hf = *(short8*)(&smem[0] + hrow * 128 + (kbyte ^ ((l & 7) << 4)));
      c2 = __builtin_amdgcn_mfma_f32_16x16x32_bf16(hf, ks2 ? a2_1 : a2_0, c2, 0, 0, 0);
    }
    // thread owns n = wv_*16+l15, h = hc*128 + hg*16 + lg*4 + (0..3)
    int hl = hg * 16 + lg * 4;
    int hbase = hc * 128 + hl;
    f32x4 ncv = *(const f32x4*)(ncrow + hbase);
    f32x4 qv  = *(const f32x4*)(&q2nL[hl]);
    *(f32x4*)(orow + hbase)          = ncv;
    *(f32x4*)(orow + HH + hbase)     = c2;
    *(f32x4*)(orow + 2 * HH + hbase) = ncv * c2;
    *(f32x4*)(orow + 2304 + hbase)   = ncv * qv;
  }
}

extern "C" void kernel_launch(void* const* d_in, const int* in_sizes, int n_in,
                              void* d_out, int out_size, void* d_ws, size_t ws_size,
                              hipStream_t stream) {
  (void)in_sizes; (void)n_in; (void)out_size; (void)ws_size;
  const float* nc = (const float*)d_in[0];
  const float* qc = (const float*)d_in[1];
  const float* w  = (const float*)d_in[3];
  float* out = (float*)d_out;
  char* ws = (char*)d_ws;
  unsigned short* qwB = (unsigned short*)(ws);                 // 3,145,728 B (pre-swizzled)
  unsigned short* qcT = (unsigned short*)(ws + 3145728);       // 3,145,728 B (pre-swizzled)
  float* sqv     = (float*)(ws + 6291456);                     // 8 KB
  float* partial = (float*)(ws + 6299648);                     // 1,572,864 B
  float* mtse    = (float*)(ws + 7872512);                     // 4 KB
  unsigned short* probs = (unsigned short*)(ws + 7876608);     // 4,194,304 B

  k_prep<<<2048, 256, 0, stream>>>(qc, w, qwB, qcT, sqv);
  k_sim<<<512, 256, 0, stream>>>(nc, qwB, sqv, partial, mtse, probs);
  k_out<<<3072, 256, 0, stream>>>(nc, qcT, probs, partial, mtse, out);
}